// Round 1
// 477.754 us; speedup vs baseline: 1.0112x; 1.0112x over previous
//
#include <hip/hip_runtime.h>
#include <cmath>

#define HH 1024
#define BB 64

// d_out layout: c_new (B*H*H) | n_new (B*H) | m_new (B) | h (B*H)
#define C_ELEMS ((size_t)BB * HH * HH)

typedef float f4 __attribute__((ext_vector_type(4)));

__device__ __forceinline__ float sigm(float v) { return 1.0f / (1.0f + expf(-v)); }

// ---------------- Kernel A: conv+silu -> qk ; gates i/f ; m_new ----------------
__global__ __launch_bounds__(256) void kA(
    const float* __restrict__ x, const float* __restrict__ m,
    const float* __restrict__ cw, const float* __restrict__ cb,
    const float* __restrict__ Wi, const float* __restrict__ bi,
    const float* __restrict__ Wf, const float* __restrict__ bf,
    float* __restrict__ qk, float* __restrict__ ig,
    float* __restrict__ fg, float* __restrict__ m_out)
{
    int b = blockIdx.x;
    int tid = threadIdx.x;
    const float* xb = x + (size_t)b * HH;
    float w0 = cw[0], w1 = cw[1], w2 = cw[2], w3 = cw[3], cbv = cb[0];
    int j4 = tid * 4;
    float4 xv = *(const float4*)&xb[j4];
    float xm1 = (tid > 0) ? xb[j4 - 1] : 0.f;
    float xp4 = (tid < 255) ? xb[j4 + 4] : 0.f;
    float xp5 = (tid < 255) ? xb[j4 + 5] : 0.f;
    // SAME pad k=4: pad_lo=1 -> out[j] = w0*x[j-1]+w1*x[j]+w2*x[j+1]+w3*x[j+2]
    float s0 = cbv + w0 * xm1  + w1 * xv.x + w2 * xv.y + w3 * xv.z;
    float s1 = cbv + w0 * xv.x + w1 * xv.y + w2 * xv.z + w3 * xv.w;
    float s2 = cbv + w0 * xv.y + w1 * xv.z + w2 * xv.w + w3 * xp4;
    float s3 = cbv + w0 * xv.z + w1 * xv.w + w2 * xp4  + w3 * xp5;
    float4 q;
    q.x = s0 * sigm(s0); q.y = s1 * sigm(s1);
    q.z = s2 * sigm(s2); q.w = s3 * sigm(s3);
    *(float4*)&qk[(size_t)b * HH + j4] = q;

    float4 wi4 = *(const float4*)&Wi[j4];
    float4 wf4 = *(const float4*)&Wf[j4];
    float pi = xv.x * wi4.x + xv.y * wi4.y + xv.z * wi4.z + xv.w * wi4.w;
    float pf = xv.x * wf4.x + xv.y * wf4.y + xv.z * wf4.z + xv.w * wf4.w;

    // wave shuffle reduce (4 waves), then 1 barrier + tiny combine
    #pragma unroll
    for (int o = 32; o > 0; o >>= 1) {
        pi += __shfl_down(pi, o, 64);
        pf += __shfl_down(pf, o, 64);
    }
    __shared__ float ri[4], rf[4];
    int wid = tid >> 6, lane = tid & 63;
    if (lane == 0) { ri[wid] = pi; rf[wid] = pf; }
    __syncthreads();
    if (tid == 0) {
        float it = ri[0] + ri[1] + ri[2] + ri[3] + bi[0];
        float ft = rf[0] + rf[1] + rf[2] + rf[3] + bf[0];
        float mo = m[b];
        float mn = fmaxf(ft + mo, it);
        m_out[b] = mn;
        ig[b] = expf(it - mn);
        fg[b] = expf(ft + mo - mn);
    }
}

// ---------------- Kernel B: split-K GEMMs (5 mats), partials to ws ----------------
// grid: (16 jtiles, 8 ksplits, 5 mats) = 640 blocks; block 256.
// tile: 64 b x 64 j, over 128 i. Thread: 4b x 4j register block.
__global__ __launch_bounds__(256) void kB(
    const float* __restrict__ x, const float* __restrict__ qk,
    const float* __restrict__ Wo, const float* __restrict__ Wv,
    const float* __restrict__ Wk, const float* __restrict__ Wq,
    const float* __restrict__ Wsk, float* __restrict__ part)
{
    int jt = blockIdx.x, ks = blockIdx.y, mat = blockIdx.z;
    const float* W; const float* src;
    switch (mat) {
        case 0: W = Wo;  src = x;  break;
        case 1: W = Wv;  src = x;  break;
        case 2: W = Wk;  src = qk; break;
        case 3: W = Wq;  src = qk; break;
        default: W = Wsk; src = qk; break;
    }
    int j0 = jt * 64;
    int i_base = ks * 128;
    int tid = threadIdx.x;
    int jg = tid & 15;          // 16 j-groups (4 j each)
    int bg = tid >> 4;          // 16 b-groups (4 b each)
    int b0 = bg * 4;

    __shared__ float wlds[32 * 64];     // [ii][j]
    __shared__ float xlds[32 * 68];     // [ii][b], pad 68 to break conflicts

    float acc[4][4];
    #pragma unroll
    for (int a = 0; a < 4; ++a)
        #pragma unroll
        for (int d = 0; d < 4; ++d) acc[a][d] = 0.f;

    for (int ch = 0; ch < 4; ++ch) {
        int i0 = i_base + ch * 32;
        // stage W[i0..i0+31][j0..j0+63]
        {
            int ii = tid >> 4;
            int c4 = (tid & 15) * 4;
            float4 wa = *(const float4*)&W[(size_t)(i0 + ii) * HH + j0 + c4];
            float4 wb = *(const float4*)&W[(size_t)(i0 + ii + 16) * HH + j0 + c4];
            *(float4*)&wlds[ii * 64 + c4] = wa;
            *(float4*)&wlds[(ii + 16) * 64 + c4] = wb;
        }
        // stage src[b][i0..i0+31] transposed -> xlds[ii][b]
        {
            int b = tid >> 2;
            int ii0 = (tid & 3) * 8;
            float4 xa = *(const float4*)&src[(size_t)b * HH + i0 + ii0];
            float4 xb = *(const float4*)&src[(size_t)b * HH + i0 + ii0 + 4];
            xlds[(ii0 + 0) * 68 + b] = xa.x;
            xlds[(ii0 + 1) * 68 + b] = xa.y;
            xlds[(ii0 + 2) * 68 + b] = xa.z;
            xlds[(ii0 + 3) * 68 + b] = xa.w;
            xlds[(ii0 + 4) * 68 + b] = xb.x;
            xlds[(ii0 + 5) * 68 + b] = xb.y;
            xlds[(ii0 + 6) * 68 + b] = xb.z;
            xlds[(ii0 + 7) * 68 + b] = xb.w;
        }
        __syncthreads();
        #pragma unroll
        for (int ii = 0; ii < 32; ++ii) {
            float4 wv = *(const float4*)&wlds[ii * 64 + jg * 4];
            float4 xv = *(const float4*)&xlds[ii * 68 + b0];
            acc[0][0] += xv.x * wv.x; acc[0][1] += xv.x * wv.y;
            acc[0][2] += xv.x * wv.z; acc[0][3] += xv.x * wv.w;
            acc[1][0] += xv.y * wv.x; acc[1][1] += xv.y * wv.y;
            acc[1][2] += xv.y * wv.z; acc[1][3] += xv.y * wv.w;
            acc[2][0] += xv.z * wv.x; acc[2][1] += xv.z * wv.y;
            acc[2][2] += xv.z * wv.z; acc[2][3] += xv.z * wv.w;
            acc[3][0] += xv.w * wv.x; acc[3][1] += xv.w * wv.y;
            acc[3][2] += xv.w * wv.z; acc[3][3] += xv.w * wv.w;
        }
        __syncthreads();
    }
    float* p = part + (size_t)(mat * 8 + ks) * (BB * HH);
    #pragma unroll
    for (int a = 0; a < 4; ++a) {
        float4 v = make_float4(acc[a][0], acc[a][1], acc[a][2], acc[a][3]);
        *(float4*)&p[(size_t)(b0 + a) * HH + j0 + jg * 4] = v;
    }
}

// ---------------- Kernel C: reduce partials, bias/act, n_new, dot partials ----------------
// grid: (4 segs, 64 b) = 256 blocks; block 256; thread handles 1 j (scalar, coalesced)
__global__ __launch_bounds__(256) void kC(
    const float* __restrict__ part, const float* __restrict__ n_in,
    const float* __restrict__ bo, const float* __restrict__ bv,
    const float* __restrict__ bk, const float* __restrict__ bq,
    const float* __restrict__ bsk,
    const float* __restrict__ ig, const float* __restrict__ fg,
    float* __restrict__ out_s, float* __restrict__ value_s,
    float* __restrict__ key_s, float* __restrict__ query_s,
    float* __restrict__ skip_s, float* __restrict__ dotp,
    float* __restrict__ n_out)
{
    int seg = blockIdx.x, b = blockIdx.y;
    int tid = threadIdx.x;
    int j = seg * 256 + tid;
    size_t base = (size_t)b * HH + j;
    float s0 = 0.f, s1 = 0.f, s2 = 0.f, s3 = 0.f, s4 = 0.f;
    #pragma unroll
    for (int ksp = 0; ksp < 8; ++ksp) {
        size_t o = (size_t)ksp * (BB * HH) + base;
        s0 += part[(size_t)(0 * 8) * (BB * HH) + o];
        s1 += part[(size_t)(1 * 8) * (BB * HH) + o];
        s2 += part[(size_t)(2 * 8) * (BB * HH) + o];
        s3 += part[(size_t)(3 * 8) * (BB * HH) + o];
        s4 += part[(size_t)(4 * 8) * (BB * HH) + o];
    }
    const float rsH = 0.03125f; // 1/sqrt(1024)
    float og = sigm(s0 + bo[j]);
    float vl = s1 + bv[j];
    float ky = (s2 + bk[j]) * rsH;
    float qu = s3 + bq[j];
    float sk = s4 + bsk[j];

    out_s[base]   = og;
    value_s[base] = vl;
    key_s[base]   = ky;
    query_s[base] = qu;
    skip_s[base]  = sk;

    float igv = ig[b], fgv = fg[b];
    float nn = fgv * n_in[base] + igv * ky;
    n_out[base] = nn;

    float d = nn * qu;
    #pragma unroll
    for (int o = 32; o > 0; o >>= 1) d += __shfl_down(d, o, 64);
    __shared__ float red[4];
    int wid = tid >> 6, lane = tid & 63;
    if (lane == 0) red[wid] = d;
    __syncthreads();
    if (tid == 0) dotp[b * 4 + seg] = red[0] + red[1] + red[2] + red[3];
}

// ---------------- Kernel D: stream c -> c_new (non-temporal), fused row-dot -> h ----------------
// wave per row (b,i); 4 waves per block; grid 65536/4 = 16384
__global__ __launch_bounds__(256) void kD(
    const float* __restrict__ c,
    const float* __restrict__ key_s, const float* __restrict__ query_s,
    const float* __restrict__ value_s, const float* __restrict__ out_s,
    const float* __restrict__ skip_s, const float* __restrict__ ig,
    const float* __restrict__ fg, const float* __restrict__ dotp,
    float* __restrict__ c_out, float* __restrict__ h_out)
{
    int wid = threadIdx.x >> 6;
    int lane = threadIdx.x & 63;
    int r = blockIdx.x * 4 + wid;      // r = b*H + i
    int b = r >> 10;
    float fgv = fg[b];
    float iv = ig[b] * value_s[r];
    const f4* crow = (const f4*)(c + ((size_t)r << 10));
    f4* orow = (f4*)(c_out + ((size_t)r << 10));
    const float* keyb = key_s + (size_t)b * HH;
    const float* qb = query_s + (size_t)b * HH;
    float dot = 0.f;
    #pragma unroll
    for (int kk = 0; kk < 4; ++kk) {
        int k4 = kk * 64 + lane;           // float4 index within row
        f4 c4 = __builtin_nontemporal_load(&crow[k4]);   // streaming: bypass cache reuse
        float4 kx = *(const float4*)&keyb[k4 * 4];       // hot in L2 (reused per b)
        float4 q4 = *(const float4*)&qb[k4 * 4];
        f4 cn;
        cn.x = fgv * c4.x + iv * kx.x;
        cn.y = fgv * c4.y + iv * kx.y;
        cn.z = fgv * c4.z + iv * kx.z;
        cn.w = fgv * c4.w + iv * kx.w;
        __builtin_nontemporal_store(cn, &orow[k4]);      // streaming store: no write-allocate
        dot += cn.x * q4.x + cn.y * q4.y + cn.z * q4.z + cn.w * q4.w;
    }
    #pragma unroll
    for (int d = 32; d > 0; d >>= 1) dot += __shfl_down(dot, d, 64);
    if (lane == 0) {
        float ds = dotp[b * 4 + 0] + dotp[b * 4 + 1] + dotp[b * 4 + 2] + dotp[b * 4 + 3];
        float scl = 1.0f / fmaxf(fabsf(ds), 1.0f);
        h_out[r] = out_s[r] * dot * scl + skip_s[r];
    }
}

extern "C" void kernel_launch(void* const* d_in, const int* in_sizes, int n_in,
                              void* d_out, int out_size, void* d_ws, size_t ws_size,
                              hipStream_t stream)
{
    const float* c   = (const float*)d_in[0];
    const float* n   = (const float*)d_in[1];
    const float* m   = (const float*)d_in[2];
    const float* x   = (const float*)d_in[3];
    const float* Wq  = (const float*)d_in[4];
    const float* bq  = (const float*)d_in[5];
    const float* Wk  = (const float*)d_in[6];
    const float* bk  = (const float*)d_in[7];
    const float* Wv  = (const float*)d_in[8];
    const float* bv  = (const float*)d_in[9];
    const float* cw  = (const float*)d_in[10];
    const float* cb  = (const float*)d_in[11];
    const float* Wi  = (const float*)d_in[12];
    const float* bi  = (const float*)d_in[13];
    const float* Wf  = (const float*)d_in[14];
    const float* bf  = (const float*)d_in[15];
    const float* Wo  = (const float*)d_in[16];
    const float* bo  = (const float*)d_in[17];
    const float* Wsk = (const float*)d_in[18];
    const float* bsk = (const float*)d_in[19];

    float* out = (float*)d_out;
    float* ws  = (float*)d_ws;

    const int BH = BB * HH; // 65536
    // ws layout (floats)
    float* qk      = ws;                    // BH
    float* ig      = ws + BH;               // 64
    float* fg      = ig + BB;               // 64
    float* dotp    = fg + BB;               // 256
    float* fin     = dotp + 256;
    float* out_s   = fin + 0 * BH;
    float* value_s = fin + 1 * BH;
    float* key_s   = fin + 2 * BH;
    float* query_s = fin + 3 * BH;
    float* skip_s  = fin + 4 * BH;
    float* part    = fin + 5 * BH;          // 40 * BH

    float* c_out = out;
    float* n_out = out + C_ELEMS;
    float* m_out = out + C_ELEMS + BH;
    float* h_out = m_out + BB;

    kA<<<BB, 256, 0, stream>>>(x, m, cw, cb, Wi, bi, Wf, bf, qk, ig, fg, m_out);
    dim3 gB(16, 8, 5);
    kB<<<gB, 256, 0, stream>>>(x, qk, Wo, Wv, Wk, Wq, Wsk, part);
    dim3 gC(4, BB);
    kC<<<gC, 256, 0, stream>>>(part, n, bo, bv, bk, bq, bsk, ig, fg,
                               out_s, value_s, key_s, query_s, skip_s, dotp, n_out);
    kD<<<BH / 4, 256, 0, stream>>>(c, key_s, query_s, value_s, out_s, skip_s,
                                   ig, fg, dotp, c_out, h_out);
}